// Round 16
// baseline (387.026 us; speedup 1.0000x reference)
//
#include <hip/hip_runtime.h>

// VectorQuantizer: bf16-MFMA approximate distance pass + margin shortlist +
// exact f32 rescore + gather/losses.  N=32768 rows, D=256, K=8192 codes.
//
// R16 = R15 (334us best: conflict-free fragment-major, 0 conflicts) with
// vq_mfma moved to the 256-thread envelope to buy zi=2:
//   R15 wall/chunk/CU: LDS 2560 + VALU 1150 + MFMA 1030 (lockstep sum).
//   LDS reads scale 1/zi. zi=2 needs af[2][8]=64+ VGPR -> impossible at
//   512thr (<=64 VGPR for 2blk, R14), fine at 256thr (R6: 160 VGPR clean;
//   m69: VGPR<=256 still allows 8 waves/CU). Config: BM=64 = wm2 x zi2 x 16,
//   4 waves (wm2 x wn2), ci=2, chunk=64, Bs 2x32KB, 2 blk/CU -> the 2
//   waves/SIMD are from DIFFERENT blocks (desync, R8's mechanism).
//   LDS traffic 10.5 -> 6.3 GB. Numerics/fragments/epilogue identical.
// Also: gather grid 256->512 (64 rows/block) for latency hiding.

#define NROWS 32768
#define NE    8192
#define DDIM  256
#define BM    64
#define CAP   64
#define MARGIN 1e-4f
#define NCH   (NE / 64)    // 128 chunks of 64 candidates

typedef __attribute__((ext_vector_type(8))) short bf16x8;
typedef __attribute__((ext_vector_type(4))) float f32x4;
typedef unsigned short u16;

__device__ __forceinline__ u16 f2bf(float f) {
  unsigned x = __float_as_uint(f);
  return (u16)((x + 0x7fffu + ((x >> 16) & 1u)) >> 16);   // RNE
}

__device__ __forceinline__ void gload_lds16(const void* g, void* l) {
  __builtin_amdgcn_global_load_lds(
      (const __attribute__((address_space(1))) void*)g,
      (__attribute__((address_space(3))) void*)l, 16, 0, 0);
}

// ---------------- row norms: a[n] = sum z^2, c[k] = sum e^2 -------------
__global__ __launch_bounds__(256)
void vq_norms(const float* __restrict__ z, const float* __restrict__ emb,
              float* __restrict__ arow, float* __restrict__ cemb) {
  int gid  = blockIdx.x * 256 + threadIdx.x;
  int wid  = gid >> 6;
  int lane = threadIdx.x & 63;
  const float* src;
  float* dst;
  if (wid < NROWS) { src = z + (size_t)wid * DDIM;   dst = arow + wid; }
  else             { int r = wid - NROWS;
                     src = emb + (size_t)r * DDIM;   dst = cemb + r; }
  float4 v = *reinterpret_cast<const float4*>(src + lane * 4);
  float s = v.x * v.x + v.y * v.y;
  s += v.z * v.z;
  s += v.w * v.w;
  #pragma unroll
  for (int off = 1; off < 64; off <<= 1) s += __shfl_xor(s, off, 64);
  if (lane == 0) *dst = s;
}

// -------- emb f32 -> bf16, FRAGMENT-MAJOR (R13/R14/R15-verified) --------
// 16B-chunk o: g16 = o>>9 (16-cand group), s = (o>>6)&7 (k-tile),
// lane l = o&63 (lg=l>>4, l15=l&15). Chunk holds cand (g16*16+l15),
// k-range [(s*4+lg)*8, +8). Fragment (g16,s) = 1KB contiguous.
__global__ __launch_bounds__(256)
void vq_cvt(const float* __restrict__ emb, u16* __restrict__ e16) {
  int o   = blockIdx.x * 256 + threadIdx.x;   // 0 .. NE*32-1
  int g16 = o >> 9;
  int r   = o & 511;
  int s   = r >> 6;
  int l   = r & 63;
  int lg  = l >> 4, l15 = l & 15;
  int c   = g16 * 16 + l15;
  int kc  = s * 4 + lg;
  const float* src = emb + (size_t)c * DDIM + kc * 8;
  float4 v0 = *reinterpret_cast<const float4*>(src);
  float4 v1 = *reinterpret_cast<const float4*>(src + 4);
  u16 ov[8] = {f2bf(v0.x), f2bf(v0.y), f2bf(v0.z), f2bf(v0.w),
               f2bf(v1.x), f2bf(v1.y), f2bf(v1.z), f2bf(v1.w)};
  *reinterpret_cast<bf16x8*>(e16 + (size_t)o * 8) =
      *reinterpret_cast<bf16x8*>(ov);
}

// ---------------- MFMA approx pass + shortlist --------------------------
// 256 thr, 4 waves: wm=wid>>1 (2 x 32-row half), wn=wid&1 (2 x 32-cand).
// zi=2 row-tiles in regs, ci=2 -> 16 reads / 32 MFMAs per wave per chunk.
__global__ __launch_bounds__(256)
void vq_mfma(const float* __restrict__ z, const u16* __restrict__ e16,
             const float* __restrict__ arow, const float* __restrict__ cemb,
             unsigned* __restrict__ cnt, int* __restrict__ list) {
  __shared__ u16 Bs[2][64 * DDIM];   // 2 x 32 KB, fragment-major

  const int t    = threadIdx.x;
  const int R0   = blockIdx.x * BM;
  const int lane = t & 63;
  const int wid  = t >> 6;          // 0..3
  const int wm   = wid >> 1;        // 0..1 : 32-row half
  const int wn   = wid & 1;         // 0..1 : 32-cand half
  const int l15  = lane & 15;
  const int lg   = lane >> 4;       // 0..3

  // ---- A fragments: 2 row-tiles straight from global z, in registers ----
  // af[zi][s] = z-row (R0+wm*32+zi*16+l15), global k-chunk (s*4+lg)*8..+8
  bf16x8 af[2][8];
  float  a_r[2], runmin[2];
  #pragma unroll
  for (int zi = 0; zi < 2; ++zi) {
    const int row = R0 + wm * 32 + zi * 16 + l15;
    const float* zr = z + (size_t)row * DDIM;
    #pragma unroll
    for (int s = 0; s < 8; ++s) {
      const float* src = zr + (s * 4 + lg) * 8;
      float4 v0 = *reinterpret_cast<const float4*>(src);
      float4 v1 = *reinterpret_cast<const float4*>(src + 4);
      u16 o[8] = {f2bf(v0.x), f2bf(v0.y), f2bf(v0.z), f2bf(v0.w),
                  f2bf(v1.x), f2bf(v1.y), f2bf(v1.z), f2bf(v1.w)};
      af[zi][s] = *reinterpret_cast<bf16x8*>(o);
    }
    a_r[zi] = arow[row];
    runmin[zi] = 3.4e38f;
  }

  // ---- prologue: DMA chunk 0 -> Bs[0] (32 frag-KB; wave stages 8) ----
  {
    const char* src = (const char*)e16;
    #pragma unroll
    for (int i = 0; i < 8; ++i) {
      int f = wid * 8 + i;
      gload_lds16(src + f * 1024 + lane * 16, (char*)&Bs[0][0] + f * 1024);
    }
  }
  __syncthreads();   // drains prologue DMA

  for (int ch = 0; ch < NCH; ++ch) {
    const int buf = ch & 1;
    const int C0  = ch * 64;

    // ---- issue next chunk's DMA first (whole chunk to land) ----
    if (ch + 1 < NCH) {
      const char* src = (const char*)e16 + (size_t)(ch + 1) * 32768;
      char* dst = (char*)&Bs[buf ^ 1][0];
      #pragma unroll
      for (int i = 0; i < 8; ++i) {
        int f = wid * 8 + i;
        gload_lds16(src + f * 1024 + lane * 16, dst + f * 1024);
      }
    }

    // ---- hoisted epilogue constants (L2 latency hides under MFMAs) ----
    float4 cvv[2];
    #pragma unroll
    for (int ci = 0; ci < 2; ++ci)
      cvv[ci] = *reinterpret_cast<const float4*>(
          &cemb[C0 + wn * 32 + ci * 16 + lg * 4]);

    // ---- compute: contiguous 1KB fragment reads, 32 MFMAs ----
    f32x4 acc[2][2];
    #pragma unroll
    for (int zi = 0; zi < 2; ++zi)
      #pragma unroll
      for (int ci = 0; ci < 2; ++ci)
        acc[zi][ci] = (f32x4){0.f, 0.f, 0.f, 0.f};

    const u16* Bp = &Bs[buf][0];
    #pragma unroll
    for (int s = 0; s < 8; ++s) {
      // frag (g16l = wn*2+ci, s): bytes (g16l*8+s)*1024 + lane*16
      bf16x8 bfr[2];
      #pragma unroll
      for (int ci = 0; ci < 2; ++ci)
        bfr[ci] = *reinterpret_cast<const bf16x8*>(
            &Bp[((wn * 2 + ci) * 8 + s) * 512 + lane * 8]);
      #pragma unroll
      for (int ci = 0; ci < 2; ++ci)
        #pragma unroll
        for (int zi = 0; zi < 2; ++zi)
          acc[zi][ci] = __builtin_amdgcn_mfma_f32_16x16x32_bf16(
              bfr[ci], af[zi][s], acc[zi][ci], 0, 0, 0);
    }

    // ---- epilogue (R15-verified): row mins, 2 shuffles/zi, appends ----
    // lane's z-row (zi) = R0 + wm*32 + zi*16 + l15
    // lane's cand (ci,r) = C0 + wn*32 + ci*16 + lg*4 + r
    #pragma unroll
    for (int zi = 0; zi < 2; ++zi) {
      float lm = 3.4e38f;
      #pragma unroll
      for (int ci = 0; ci < 2; ++ci)
        #pragma unroll
        for (int r = 0; r < 4; ++r) {
          float dd = fmaf(-2.0f, acc[zi][ci][r], a_r[zi]) + cvv[ci][r];
          lm = fminf(lm, dd);
        }
      float gm = fminf(lm, __shfl_xor(lm, 16, 64));
      gm = fminf(gm, __shfl_xor(gm, 32, 64));
      runmin[zi] = fminf(runmin[zi], gm);
      float thr = runmin[zi] + MARGIN;
      if (lm <= thr) {
        // u-form test (R5-verified): d<=thr <=> u >= 0.5*(a+c-thr)
        const int rowg = R0 + wm * 32 + zi * 16 + l15;
        const float h = 0.5f * (a_r[zi] - thr);
        #pragma unroll
        for (int ci = 0; ci < 2; ++ci)
          #pragma unroll
          for (int r = 0; r < 4; ++r)
            if (acc[zi][ci][r] >= fmaf(0.5f, cvv[ci][r], h)) {
              int k = C0 + wn * 32 + ci * 16 + lg * 4 + r;
              unsigned p = atomicAdd(&cnt[rowg], 1u);
              if (p < CAP) list[(size_t)rowg * CAP + p] = k;
            }
      }
    }

    __syncthreads();   // drains this chunk's reads + next chunk's DMA
  }
}

// ---------------- exact f32 rescore of shortlists -----------------------
__global__ __launch_bounds__(256)
void vq_rescore(const float* __restrict__ z, const float* __restrict__ emb,
                const float* __restrict__ arow, const float* __restrict__ cemb,
                const unsigned* __restrict__ cnt, const int* __restrict__ list,
                int* __restrict__ ws_idx) {
  const int row  = blockIdx.x * 4 + (threadIdx.x >> 6);
  const int lane = threadIdx.x & 63;
  const float a  = arow[row];
  const float4 zv = *reinterpret_cast<const float4*>(
      z + (size_t)row * DDIM + lane * 4);
  unsigned n = cnt[row];
  float bd = 3.4e38f;
  int   bk = 0;

  const bool fullscan = (n == 0 || n > CAP);
  const int  m = fullscan ? NE : (int)n;
  for (int i = 0; i < m; ++i) {
    int k = fullscan ? i : list[(size_t)row * CAP + i];
    const float4 ev = *reinterpret_cast<const float4*>(
        emb + (size_t)k * DDIM + lane * 4);
    float p = zv.x * ev.x;
    p = fmaf(zv.y, ev.y, p);
    p = fmaf(zv.z, ev.z, p);
    p = fmaf(zv.w, ev.w, p);
    #pragma unroll
    for (int off = 1; off < 64; off <<= 1) p += __shfl_xor(p, off, 64);
    float d = fmaf(-2.0f, p, a) + cemb[k];   // exact ref chain
    if (d < bd || (d == bd && k < bk)) { bd = d; bk = k; }
  }
  if (lane == 0) ws_idx[row] = bk;
}

// ---------------- gather + STE + losses ---------------------------------
__global__ __launch_bounds__(256)
void vq_gather(const float* __restrict__ z, const float* __restrict__ emb,
               const int* __restrict__ ws_idx,
               float* __restrict__ out_zq, float* __restrict__ out_idx,
               double* __restrict__ loss_accum) {
  __shared__ float part[4];
  const int t  = threadIdx.x;
  const int R0 = blockIdx.x * 64;
  float lsum = 0.0f;
  for (int rr = 0; rr < 64; ++rr) {
    const int kb = ws_idx[R0 + rr];
    const size_t gi = (size_t)(R0 + rr) * DDIM + t;
    const float zv = z[gi];
    const float qv = emb[(size_t)kb * DDIM + t];
    const float diff = qv - zv;              // z_q - z
    out_zq[gi] = zv + diff;                  // z + (z_q - z) exact chain
    lsum = fmaf(diff, diff, lsum);
  }
  #pragma unroll
  for (int off = 1; off < 64; off <<= 1) lsum += __shfl_xor(lsum, off, 64);
  if ((t & 63) == 0) part[t >> 6] = lsum;
  __syncthreads();
  if (t == 0) {
    float tot = (part[0] + part[1]) + (part[2] + part[3]);
    atomicAdd(loss_accum, (double)tot);
  }
  if (t < 64) out_idx[R0 + t] = (float)ws_idx[R0 + t];
}

// ---------------- scalar losses -----------------------------------------
__global__ void vq_finalize(const double* __restrict__ loss_accum,
                            float* __restrict__ out_losses) {
  double m = *loss_accum / (double)((size_t)NROWS * DDIM);
  out_losses[0] = (float)(0.25 * m);   // loss_commit = BETA * mse
  out_losses[1] = (float)m;            // loss_codebook
}

extern "C" void kernel_launch(void* const* d_in, const int* in_sizes, int n_in,
                              void* d_out, int out_size, void* d_ws, size_t ws_size,
                              hipStream_t stream) {
  const float* z   = (const float*)d_in[0];
  const float* emb = (const float*)d_in[1];
  float* out        = (float*)d_out;
  float* out_zq     = out;                            // [8388608]
  float* out_losses = out + (size_t)NROWS * DDIM;     // [2]
  float* out_idx    = out + (size_t)NROWS * DDIM + 2; // [32768] as f32

  // persistent ws scratch (small)
  double* loss_accum = (double*)d_ws;
  float*  arow   = (float*)((char*)d_ws + 256);
  float*  cemb   = arow + NROWS;
  int*    ws_idx = (int*)(cemb + NE);

  // large scratch carved from d_out's z_q region (fully rewritten each call;
  // vq_gather overwrites after all readers are done => deterministic)
  u16*      e16  = (u16*)d_out;                              // [0, 4MB)
  int*      list = (int*)((char*)d_out + (4 << 20));         // [4MB, 12MB) CAP=64
  unsigned* cnt  = (unsigned*)((char*)d_out + (12 << 20));   // [12MB, +128KB)

  hipMemsetAsync(d_ws, 0, 8, stream);
  hipMemsetAsync(cnt, 0, NROWS * sizeof(unsigned), stream);
  vq_norms<<<(NROWS + NE) / 4, 256, 0, stream>>>(z, emb, arow, cemb);
  vq_cvt<<<NE * 32 / 256, 256, 0, stream>>>(emb, e16);
  vq_mfma<<<NROWS / BM, 256, 0, stream>>>(z, e16, arow, cemb, cnt, list);
  vq_rescore<<<NROWS / 4, 256, 0, stream>>>(z, emb, arow, cemb, cnt, list, ws_idx);
  vq_gather<<<NROWS / 64, 256, 0, stream>>>(z, emb, ws_idx,
                                            out_zq, out_idx, loss_accum);
  vq_finalize<<<1, 1, 0, stream>>>(loss_accum, out_losses);
}

// Round 18
// 321.471 us; speedup vs baseline: 1.2039x; 1.2039x over previous
//
#include <hip/hip_runtime.h>

// VectorQuantizer: bf16-MFMA approximate distance pass + margin shortlist +
// exact f32 rescore + gather/losses.  N=32768, D=256, K=8192.
//
// R18 = R15 (334us proven base) + ONE change: vq_mfma epilogue moved AFTER
// __syncthreads (regs+global only -> append atomic tails overlap other
// waves' next-chunk compute; barrier placement vs all LDS accesses
// unchanged). R17's rescore+gather fusion is ABANDONED: it crashed on an
// aliasing bug (list/cnt live under out_zq rows 4096..12415; fused kernel
// wrote z_q while other blocks still read list -> garbage k -> OOB fault).
// Separate rescore (ws_idx) + gather (512 blocks x 64 rows, R16-verified)
// restore the ordering that makes the d_out carve safe.

#define NROWS 32768
#define NE    8192
#define DDIM  256
#define BM    64
#define CAP   64
#define MARGIN 1e-4f
#define NCH   (NE / 64)    // 128 chunks of 64 candidates

typedef __attribute__((ext_vector_type(8))) short bf16x8;
typedef __attribute__((ext_vector_type(4))) float f32x4;
typedef unsigned short u16;

__device__ __forceinline__ u16 f2bf(float f) {
  unsigned x = __float_as_uint(f);
  return (u16)((x + 0x7fffu + ((x >> 16) & 1u)) >> 16);   // RNE
}

__device__ __forceinline__ void gload_lds16(const void* g, void* l) {
  __builtin_amdgcn_global_load_lds(
      (const __attribute__((address_space(1))) void*)g,
      (__attribute__((address_space(3))) void*)l, 16, 0, 0);
}

// ---------------- row norms: a[n] = sum z^2, c[k] = sum e^2 -------------
__global__ __launch_bounds__(256)
void vq_norms(const float* __restrict__ z, const float* __restrict__ emb,
              float* __restrict__ arow, float* __restrict__ cemb) {
  int gid  = blockIdx.x * 256 + threadIdx.x;
  int wid  = gid >> 6;
  int lane = threadIdx.x & 63;
  const float* src;
  float* dst;
  if (wid < NROWS) { src = z + (size_t)wid * DDIM;   dst = arow + wid; }
  else             { int r = wid - NROWS;
                     src = emb + (size_t)r * DDIM;   dst = cemb + r; }
  float4 v = *reinterpret_cast<const float4*>(src + lane * 4);
  float s = v.x * v.x + v.y * v.y;
  s += v.z * v.z;
  s += v.w * v.w;
  #pragma unroll
  for (int off = 1; off < 64; off <<= 1) s += __shfl_xor(s, off, 64);
  if (lane == 0) *dst = s;
}

// -------- emb f32 -> bf16, FRAGMENT-MAJOR (R13..R16-verified) -----------
// 16B-chunk o: g16 = o>>9 (16-cand group), s = (o>>6)&7 (k-tile),
// lane l = o&63 (lg=l>>4, l15=l&15). Chunk holds cand (g16*16+l15),
// k-range [(s*4+lg)*8, +8). Fragment (g16,s) = 1KB contiguous.
__global__ __launch_bounds__(256)
void vq_cvt(const float* __restrict__ emb, u16* __restrict__ e16) {
  int o   = blockIdx.x * 256 + threadIdx.x;   // 0 .. NE*32-1
  int g16 = o >> 9;
  int r   = o & 511;
  int s   = r >> 6;
  int l   = r & 63;
  int lg  = l >> 4, l15 = l & 15;
  int c   = g16 * 16 + l15;
  int kc  = s * 4 + lg;
  const float* src = emb + (size_t)c * DDIM + kc * 8;
  float4 v0 = *reinterpret_cast<const float4*>(src);
  float4 v1 = *reinterpret_cast<const float4*>(src + 4);
  u16 ov[8] = {f2bf(v0.x), f2bf(v0.y), f2bf(v0.z), f2bf(v0.w),
               f2bf(v1.x), f2bf(v1.y), f2bf(v1.z), f2bf(v1.w)};
  *reinterpret_cast<bf16x8*>(e16 + (size_t)o * 8) =
      *reinterpret_cast<bf16x8*>(ov);
}

// ---------------- MFMA approx pass + shortlist (R15 + post-barrier epi) --
// 8 waves: wm=wid>>1 (4 x 16-row group), wn=wid&1 (2 x 32-cand half).
__global__ __launch_bounds__(512, 4)
void vq_mfma(const float* __restrict__ z, const u16* __restrict__ e16,
             const float* __restrict__ arow, const float* __restrict__ cemb,
             unsigned* __restrict__ cnt, int* __restrict__ list) {
  __shared__ u16 Bs[2][64 * DDIM];   // 2 x 32 KB, fragment-major

  const int t    = threadIdx.x;
  const int R0   = blockIdx.x * BM;
  const int lane = t & 63;
  const int wid  = t >> 6;          // 0..7
  const int wm   = wid >> 1;        // 0..3 : 16-row group
  const int wn   = wid & 1;         // 0..1 : 32-cand half
  const int l15  = lane & 15;
  const int lg   = lane >> 4;       // 0..3

  // ---- A fragments: straight from global z, f32 -> bf16, in registers ----
  bf16x8 af[8];
  const int row = R0 + wm * 16 + l15;
  {
    const float* zr = z + (size_t)row * DDIM;
    #pragma unroll
    for (int s = 0; s < 8; ++s) {
      const float* src = zr + (s * 4 + lg) * 8;
      float4 v0 = *reinterpret_cast<const float4*>(src);
      float4 v1 = *reinterpret_cast<const float4*>(src + 4);
      u16 o[8] = {f2bf(v0.x), f2bf(v0.y), f2bf(v0.z), f2bf(v0.w),
                  f2bf(v1.x), f2bf(v1.y), f2bf(v1.z), f2bf(v1.w)};
      af[s] = *reinterpret_cast<bf16x8*>(o);
    }
  }
  const float a_r = arow[row];
  float runmin = 3.4e38f;

  // ---- prologue: DMA chunk 0 -> Bs[0] ----
  {
    const char* src = (const char*)e16;
    #pragma unroll
    for (int i = 0; i < 4; ++i) {
      int f = wid * 4 + i;
      gload_lds16(src + f * 1024 + lane * 16, (char*)&Bs[0][0] + f * 1024);
    }
  }
  __syncthreads();   // drains prologue DMA

  for (int ch = 0; ch < NCH; ++ch) {
    const int buf = ch & 1;
    const int C0  = ch * 64;

    // ---- issue next chunk's DMA first (whole chunk to land) ----
    if (ch + 1 < NCH) {
      const char* src = (const char*)e16 + (size_t)(ch + 1) * 32768;
      char* dst = (char*)&Bs[buf ^ 1][0];
      #pragma unroll
      for (int i = 0; i < 4; ++i) {
        int f = wid * 4 + i;
        gload_lds16(src + f * 1024 + lane * 16, dst + f * 1024);
      }
    }

    // ---- hoisted epilogue constants (live across the barrier in regs) ----
    float4 cvv[2];
    #pragma unroll
    for (int ci = 0; ci < 2; ++ci)
      cvv[ci] = *reinterpret_cast<const float4*>(
          &cemb[C0 + wn * 32 + ci * 16 + lg * 4]);

    // ---- compute: contiguous 1KB fragment reads, 16 MFMAs ----
    f32x4 acc[2];
    acc[0] = (f32x4){0.f, 0.f, 0.f, 0.f};
    acc[1] = (f32x4){0.f, 0.f, 0.f, 0.f};

    const u16* Bp = &Bs[buf][0];
    #pragma unroll
    for (int s = 0; s < 8; ++s) {
      bf16x8 bfr[2];
      #pragma unroll
      for (int ci = 0; ci < 2; ++ci)
        bfr[ci] = *reinterpret_cast<const bf16x8*>(
            &Bp[((wn * 2 + ci) * 8 + s) * 512 + lane * 8]);
      #pragma unroll
      for (int ci = 0; ci < 2; ++ci)
        acc[ci] = __builtin_amdgcn_mfma_f32_16x16x32_bf16(
            bfr[ci], af[s], acc[ci], 0, 0, 0);
    }

    __syncthreads();   // compute(buf) done by ALL waves; next DMA drained

    // ---- POST-BARRIER epilogue (regs + global only, no LDS):
    //      atomic-append tails overlap other waves' next-chunk compute ----
    float lm = 3.4e38f;
    #pragma unroll
    for (int ci = 0; ci < 2; ++ci)
      #pragma unroll
      for (int r = 0; r < 4; ++r) {
        float dd = fmaf(-2.0f, acc[ci][r], a_r) + cvv[ci][r];
        lm = fminf(lm, dd);
      }
    float gm = fminf(lm, __shfl_xor(lm, 16, 64));
    gm = fminf(gm, __shfl_xor(gm, 32, 64));
    runmin = fminf(runmin, gm);
    float thr = runmin + MARGIN;
    if (lm <= thr) {
      // u-form test (R5-verified): d<=thr <=> u >= 0.5*(a+c-thr)
      const float h = 0.5f * (a_r - thr);
      #pragma unroll
      for (int ci = 0; ci < 2; ++ci)
        #pragma unroll
        for (int r = 0; r < 4; ++r)
          if (acc[ci][r] >= fmaf(0.5f, cvv[ci][r], h)) {
            int k = C0 + wn * 32 + ci * 16 + lg * 4 + r;
            unsigned p = atomicAdd(&cnt[row], 1u);
            if (p < CAP) list[(size_t)row * CAP + p] = k;
          }
    }
  }
}

// ---------------- exact f32 rescore of shortlists (R15-verified) --------
__global__ __launch_bounds__(256)
void vq_rescore(const float* __restrict__ z, const float* __restrict__ emb,
                const float* __restrict__ arow, const float* __restrict__ cemb,
                const unsigned* __restrict__ cnt, const int* __restrict__ list,
                int* __restrict__ ws_idx) {
  const int row  = blockIdx.x * 4 + (threadIdx.x >> 6);
  const int lane = threadIdx.x & 63;
  const float a  = arow[row];
  const float4 zv = *reinterpret_cast<const float4*>(
      z + (size_t)row * DDIM + lane * 4);
  unsigned n = cnt[row];
  float bd = 3.4e38f;
  int   bk = 0;

  const bool fullscan = (n == 0 || n > CAP);
  const int  m = fullscan ? NE : (int)n;
  for (int i = 0; i < m; ++i) {
    int k = fullscan ? i : list[(size_t)row * CAP + i];
    const float4 ev = *reinterpret_cast<const float4*>(
        emb + (size_t)k * DDIM + lane * 4);
    float p = zv.x * ev.x;
    p = fmaf(zv.y, ev.y, p);
    p = fmaf(zv.z, ev.z, p);
    p = fmaf(zv.w, ev.w, p);
    #pragma unroll
    for (int off = 1; off < 64; off <<= 1) p += __shfl_xor(p, off, 64);
    float d = fmaf(-2.0f, p, a) + cemb[k];   // exact ref chain
    if (d < bd || (d == bd && k < bk)) { bd = d; bk = k; }
  }
  if (lane == 0) ws_idx[row] = bk;
}

// ---------------- gather + STE + losses (R16-verified, 64 rows/blk) -----
__global__ __launch_bounds__(256)
void vq_gather(const float* __restrict__ z, const float* __restrict__ emb,
               const int* __restrict__ ws_idx,
               float* __restrict__ out_zq, float* __restrict__ out_idx,
               double* __restrict__ loss_accum) {
  __shared__ float part[4];
  const int t  = threadIdx.x;
  const int R0 = blockIdx.x * 64;
  float lsum = 0.0f;
  for (int rr = 0; rr < 64; ++rr) {
    const int kb = ws_idx[R0 + rr];
    const size_t gi = (size_t)(R0 + rr) * DDIM + t;
    const float zv = z[gi];
    const float qv = emb[(size_t)kb * DDIM + t];
    const float diff = qv - zv;              // z_q - z
    out_zq[gi] = zv + diff;                  // z + (z_q - z) exact chain
    lsum = fmaf(diff, diff, lsum);
  }
  #pragma unroll
  for (int off = 1; off < 64; off <<= 1) lsum += __shfl_xor(lsum, off, 64);
  if ((t & 63) == 0) part[t >> 6] = lsum;
  __syncthreads();
  if (t == 0) {
    float tot = (part[0] + part[1]) + (part[2] + part[3]);
    atomicAdd(loss_accum, (double)tot);
  }
  if (t < 64) out_idx[R0 + t] = (float)ws_idx[R0 + t];
}

// ---------------- scalar losses -----------------------------------------
__global__ void vq_finalize(const double* __restrict__ loss_accum,
                            float* __restrict__ out_losses) {
  double m = *loss_accum / (double)((size_t)NROWS * DDIM);
  out_losses[0] = (float)(0.25 * m);   // loss_commit = BETA * mse
  out_losses[1] = (float)m;            // loss_codebook
}

extern "C" void kernel_launch(void* const* d_in, const int* in_sizes, int n_in,
                              void* d_out, int out_size, void* d_ws, size_t ws_size,
                              hipStream_t stream) {
  const float* z   = (const float*)d_in[0];
  const float* emb = (const float*)d_in[1];
  float* out        = (float*)d_out;
  float* out_zq     = out;                            // [8388608]
  float* out_losses = out + (size_t)NROWS * DDIM;     // [2]
  float* out_idx    = out + (size_t)NROWS * DDIM + 2; // [32768] as f32

  // persistent ws scratch (small)
  double* loss_accum = (double*)d_ws;
  float*  arow   = (float*)((char*)d_ws + 256);
  float*  cemb   = arow + NROWS;
  int*    ws_idx = (int*)(cemb + NE);

  // large scratch carved from d_out's z_q region (fully rewritten each call;
  // vq_gather overwrites only after rescore consumed list/cnt => safe)
  u16*      e16  = (u16*)d_out;                              // [0, 4MB)
  int*      list = (int*)((char*)d_out + (4 << 20));         // [4MB, 12MB) CAP=64
  unsigned* cnt  = (unsigned*)((char*)d_out + (12 << 20));   // [12MB, +128KB)

  hipMemsetAsync(d_ws, 0, 8, stream);
  hipMemsetAsync(cnt, 0, NROWS * sizeof(unsigned), stream);
  vq_norms<<<(NROWS + NE) / 4, 256, 0, stream>>>(z, emb, arow, cemb);
  vq_cvt<<<NE * 32 / 256, 256, 0, stream>>>(emb, e16);
  vq_mfma<<<NROWS / BM, 512, 0, stream>>>(z, e16, arow, cemb, cnt, list);
  vq_rescore<<<NROWS / 4, 256, 0, stream>>>(z, emb, arow, cemb, cnt, list, ws_idx);
  vq_gather<<<NROWS / 64, 256, 0, stream>>>(z, emb, ws_idx,
                                            out_zq, out_idx, loss_accum);
  vq_finalize<<<1, 1, 0, stream>>>(loss_accum, out_losses);
}